// Round 1
// baseline (187.739 us; speedup 1.0000x reference)
//
#include <hip/hip_runtime.h>
#include <hip/hip_bf16.h>

#define H_ 64
#define W_ 2048
#define HWsz (H_*W_)
#define CIN 64
#define CTOT 68
#define COUT 64

typedef float  f32x2  __attribute__((ext_vector_type(2)));
typedef float  f32x4  __attribute__((ext_vector_type(4)));
typedef float  f32x16 __attribute__((ext_vector_type(16)));
typedef short  s16x8  __attribute__((ext_vector_type(8)));

__device__ __forceinline__ unsigned short f2bf(float f) {
    unsigned u = __builtin_bit_cast(unsigned, f);
    unsigned r = u + 0x7fffu + ((u >> 16) & 1u);   // RNE; inputs finite
    return (unsigned short)(r >> 16);
}

__device__ __forceinline__ unsigned pack2bf(float a, float b) {
    __hip_bfloat162 h = __float22bfloat162_rn(float2{a, b});   // v_cvt_pk_bf16_f32
    unsigned u;
    __builtin_memcpy(&u, &h, 4);
    return u;
}

// ---------------- prep: Wagg -> bf16 MFMA A-fragments; fold BN1 ----------------
// BwS idx lane l: o = nt*32+(l&31), ch = ks*16+(l>>5)*8+j  (A[m=o][k=ch] layout)
__global__ __launch_bounds__(256) void prep_bw(
    const float* __restrict__ Wagg,
    const float* __restrict__ W1, const float* __restrict__ g1,
    const float* __restrict__ b1, const float* __restrict__ m1,
    const float* __restrict__ v1, const float* __restrict__ W2,
    unsigned short* __restrict__ BwS, float* __restrict__ Wfold)
{
    int tid = threadIdx.x;
    if (blockIdx.x == 0) {
        if (tid < 64) {
            float s1 = g1[tid] * rsqrtf(v1[tid] + 1e-5f);
#pragma unroll
            for (int m = 0; m < 4; ++m) Wfold[tid*8 + m] = W1[tid*4 + m] * s1;
            Wfold[tid*8 + 4] = b1[tid] - m1[tid]*s1;
            Wfold[tid*8 + 5] = W2[tid];
            Wfold[tid*8 + 6] = 0.f;
            Wfold[tid*8 + 7] = 0.f;
        }
        __syncthreads();
        if (tid == 0) {
            float s = 0.f;
            for (int c = 0; c < 64; ++c) s += fmaxf(Wfold[c*8 + 4], 0.f) * Wfold[c*8 + 5];
            Wfold[512] = s;
        }
    }
    int idx = blockIdx.x * 256 + tid;
    if (idx < 4608) {
        int lane = idx & 63;
        int rest = idx >> 6;
        int nt = rest & 1;
        int ks = (rest >> 1) & 3;
        int k9 = rest >> 3;
        int o  = nt*32 + (lane & 31);
        int ch = ks*16 + (lane >> 5)*8;
        const float* src = Wagg + (size_t)o*(9*CIN) + k9*64 + ch;
        s16x8 v8;
#pragma unroll
        for (int j = 0; j < 8; ++j) v8[j] = (short)f2bf(src[j]);
        *(s16x8*)(BwS + (size_t)idx*8) = v8;
    }
}

// ---------------- mega: stage + logits + softmax + MFMA + epilogue ----------------
// Block: 512 thr (8 waves), tile = 2 rows x 64 px x 64 outputs. 4 blocks/CU
// (38,912 B LDS x4 = 152 KiB; 2048 thr = HW max -> 32 waves/CU theoretical).
// Staging: wave wv stages channel-granule wv for all 4 fe rows.
// Phase A: logits, wave=(rowq = wv>>2, tg = wv&3), 2 taps/thread packed f32x2.
// Phase B: softmax (tid<128). Phase C: MFMA, wave=(nt,rh,half); coalesced stores.
__global__ __launch_bounds__(512, 8) void mega_k(
    const float* __restrict__ x, const int* __restrict__ mask,
    const unsigned short* __restrict__ BwS, const float* __restrict__ Wfold,
    const float* __restrict__ b2p,
    const float* __restrict__ g2, const float* __restrict__ bb2,
    const float* __restrict__ m2, const float* __restrict__ v2,
    float* __restrict__ out)
{
    __shared__ __align__(16) unsigned short fe[4][8][66][8];   // 33,792 B
    __shared__ __align__(16) float sw[2][9][64];               //  4,608 B
    __shared__ __align__(16) float sbn[2][64];                 //    512 B

    const int tid = threadIdx.x;
    const int bx = blockIdx.x, by = blockIdx.y;
    const int b = by >> 5, h0 = (by & 31) << 1;
    const int w0 = bx << 6;
    const int lane = tid & 63, wv = tid >> 6;

    const float* xf = x + ((size_t)b*CTOT + 4)*HWsz;   // feat channels
    const float* xp = x + (size_t)b*CTOT*HWsz;         // pos channels 0..3
    const int*   mk = mask + (size_t)b*HWsz;

    // BN2 table (last wave)
    if (tid >= 448) {
        int o = tid - 448;
        float sc = g2[o] * rsqrtf(v2[o] + 1e-5f);
        sbn[0][o] = sc;
        sbn[1][o] = bb2[o] - m2[o]*sc;
    }

    // --- staging: interior. wave wv -> granule g=wv, rows r=0..3, lane=col ---
#pragma unroll
    for (int r = 0; r < 4; ++r) {
        int gr = h0 - 1 + r;
        uint4 q = {0u, 0u, 0u, 0u};
        if ((unsigned)gr < (unsigned)H_) {
            const float* src = xf + (size_t)(wv*8)*HWsz + (size_t)gr*W_ + w0 + lane;
            float v[8];
#pragma unroll
            for (int j = 0; j < 8; ++j) v[j] = src[(size_t)j*HWsz];
            q.x = pack2bf(v[0], v[1]); q.y = pack2bf(v[2], v[3]);
            q.z = pack2bf(v[4], v[5]); q.w = pack2bf(v[6], v[7]);
        }
        *(uint4*)&fe[r][wv][1 + lane][0] = q;
    }
    // --- halo: 64 tasks (2 cols x 4 r x 8 g) ---
    if (tid < 64) {
        int c2 = tid & 1, g = (tid >> 1) & 7, r = tid >> 4;
        int gr = h0 - 1 + r, gc = w0 - 1 + c2*65;
        uint4 q = {0u, 0u, 0u, 0u};
        if (((unsigned)gr < (unsigned)H_) && ((unsigned)gc < (unsigned)W_)) {
            const float* src = xf + (size_t)(g*8)*HWsz + (size_t)gr*W_ + gc;
            float v[8];
#pragma unroll
            for (int j = 0; j < 8; ++j) v[j] = src[(size_t)j*HWsz];
            q.x = pack2bf(v[0], v[1]); q.y = pack2bf(v[2], v[3]);
            q.z = pack2bf(v[4], v[5]); q.w = pack2bf(v[6], v[7]);
        }
        *(uint4*)&fe[r][g][c2*65][0] = q;
    }

    // --- Phase A: logits. wave = (rowq = wv>>2, tg = wv&3), 2 taps/thread ---
    const int px = tid & 63, gw = w0 + px;
    const int rowq = wv >> 2, tg = wv & 3;
    const int h = h0 + rowq;

    float pc[4];
#pragma unroll
    for (int ch = 0; ch < 4; ++ch) pc[ch] = xp[(size_t)ch*HWsz + (size_t)h*W_ + gw];

    const int ka = 2*tg + (tg >> 1);        // tg 0..3 -> taps {0,1},{2,3},{5,6},{7,8}
    f32x2 dd[4]; f32x2 mu;
#pragma unroll
    for (int i = 0; i < 2; ++i) {
        int k = ka + i;
        int r = k/3 - 1, d = k%3 - 1;
        int ih = h + r, iw = gw + d;
        bool ok = ((unsigned)ih < (unsigned)H_) && ((unsigned)iw < (unsigned)W_);
        int ihc = min(max(ih, 0), H_-1);
        int iwc = min(max(iw, 0), W_-1);
        mu[i] = ok ? (float)mk[(size_t)ihc*W_ + iwc] : 0.f;
#pragma unroll
        for (int ch = 0; ch < 4; ++ch) {
            float p = xp[(size_t)ch*HWsz + (size_t)ihc*W_ + iwc];
            dd[ch][i] = (ok ? p : 0.f) - pc[ch];   // reference zero-pads pn
        }
    }

    const f32x4* Wf4 = (const f32x4*)Wfold;
    const f32x2 z2 = {0.f, 0.f};
    f32x2 lg = z2;
#pragma unroll 8
    for (int c = 0; c < CIN; ++c) {
        f32x4 wa = Wf4[2*c];        // wave-uniform s_load
        f32x4 wb = Wf4[2*c + 1];
        f32x2 v = {wb[0], wb[0]};
        v = dd[0]*wa[0] + v;          // v_pk_fma_f32, both taps per inst
        v = dd[1]*wa[1] + v;
        v = dd[2]*wa[2] + v;
        v = dd[3]*wa[3] + v;
        v = __builtin_elementwise_max(v, z2);
        lg = v*wb[1] + lg;
    }
    float b2v = b2p[0];
    sw[rowq][ka    ][px] = (lg[0] + b2v) * mu[0];
    sw[rowq][ka + 1][px] = (lg[1] + b2v) * mu[1];
    __syncthreads();

    // --- Phase B: softmax (128 threads: row x px) ---
    if (tid < 128) {
        int rq = tid >> 6, p2 = tid & 63;
        float mu4 = (float)mk[(size_t)(h0 + rq)*W_ + w0 + p2];
        float lgv[9];
#pragma unroll
        for (int k = 0; k < 9; ++k) if (k != 4) lgv[k] = sw[rq][k][p2];
        lgv[4] = (Wfold[512] + b2v) * mu4;
        float mx = -1e30f;
#pragma unroll
        for (int k = 0; k < 9; ++k) mx = fmaxf(mx, lgv[k]);
        float s = 0.f, e[9];
#pragma unroll
        for (int k = 0; k < 9; ++k) { e[k] = __expf(lgv[k] - mx); s += e[k]; }
        float inv = 1.f / s;
#pragma unroll
        for (int k = 0; k < 9; ++k) sw[rq][k][p2] = e[k] * inv;
    }
    __syncthreads();

    // --- Phase C: MFMA. wave = (nt = wv&1, rh = (wv>>1)&1, hv = wv>>2) ---
    const int nt = wv & 1, rh = (wv >> 1) & 1, hv = wv >> 2;
    const int l31 = lane & 31, l5 = lane >> 5;
    const int hC = h0 + rh;

    const f32x16 fz16 = {0.f,0.f,0.f,0.f,0.f,0.f,0.f,0.f,0.f,0.f,0.f,0.f,0.f,0.f,0.f,0.f};
    f32x16 fin = fz16;

#pragma unroll
    for (int k9 = 0; k9 < 9; ++k9) {
        const int rr = rh + k9/3;            // fe row (fe[0] = global row h0-1)
        const int dwp = k9 % 3;

        s16x8 aw[4];
#pragma unroll
        for (int ks = 0; ks < 4; ++ks)
            aw[ks] = *(const s16x8*)(BwS + (size_t)((((k9<<2) + ks)*2 + nt) << 9) + lane*8);

        const int col = hv*32 + l31 + dwp;   // 1 + px + (dwp-1)
        f32x16 tmp = fz16;
#pragma unroll
        for (int ks = 0; ks < 4; ++ks) {
            s16x8 bfr = *(const s16x8*)&fe[rr][ks*2 + l5][col][0];
            tmp = __builtin_amdgcn_mfma_f32_32x32x16_bf16(aw[ks], bfr, tmp, 0, 0, 0);
        }
        float wsc = sw[rh][k9][hv*32 + l31];
#pragma unroll
        for (int c = 0; c < 16; ++c) fin[c] += wsc * tmp[c];
    }

    // --- epilogue: BN2 + ReLU, coalesced dword stores (128B segments) ---
    int obase = nt*32 + 4*l5;
    float* od = out + (((size_t)b*COUT + obase)*H_ + hC)*W_ + w0 + hv*32 + l31;
#pragma unroll
    for (int v = 0; v < 4; ++v) {
        f32x4 sc4 = *(const f32x4*)&sbn[0][obase + 8*v];
        f32x4 tc4 = *(const f32x4*)&sbn[1][obase + 8*v];
#pragma unroll
        for (int c = 0; c < 4; ++c)
            od[(size_t)(8*v + c)*HWsz] =
                fmaxf(fmaf(fin[4*v + c], sc4[c], tc4[c]), 0.f);
    }
}

extern "C" void kernel_launch(void* const* d_in, const int* in_sizes, int n_in,
                              void* d_out, int out_size, void* d_ws, size_t ws_size,
                              hipStream_t stream)
{
    const float* x    = (const float*)d_in[0];
    const int*   mask = (const int*)d_in[1];
    const float* W1   = (const float*)d_in[2];
    const float* g1   = (const float*)d_in[3];
    const float* b1   = (const float*)d_in[4];
    const float* m1   = (const float*)d_in[5];
    const float* v1   = (const float*)d_in[6];
    const float* W2   = (const float*)d_in[7];
    const float* b2   = (const float*)d_in[8];
    const float* Wagg = (const float*)d_in[9];
    const float* g2   = (const float*)d_in[10];
    const float* bb2  = (const float*)d_in[11];
    const float* m2   = (const float*)d_in[12];
    const float* v2   = (const float*)d_in[13];
    float* outp = (float*)d_out;

    char* ws = (char*)d_ws;
    unsigned short* BwS   = (unsigned short*)(ws + 0);      // 73,728 B
    float*          Wfold = (float*)(ws + 73728);           //  2,052 B

    hipLaunchKernelGGL(prep_bw, dim3(18), dim3(256), 0, stream,
                       Wagg, W1, g1, b1, m1, v1, W2, BwS, Wfold);
    hipLaunchKernelGGL(mega_k, dim3(W_/64, 64), dim3(512), 0, stream,
                       x, mask, BwS, Wfold, b2, g2, bb2, m2, v2, outp);
}